// Round 1
// baseline (658.535 us; speedup 1.0000x reference)
//
#include <hip/hip_runtime.h>
#include <cstdint>
#include <cstddef>

// Strategy:
//  1) absmax(x), absmax(W) via float4 grid-stride + wave shuffle-reduce +
//     atomicMax on float-as-uint bits (valid: all values non-negative).
//  2) quantize x -> int8 [M,K], W -> int8 [N,K] into d_ws (exactly matching
//     reference ops: scale = max(sat,1e-8)/127.0f; rintf(x/scale); clip).
//  3) int8 MFMA GEMM (m97 structure: 128x128 tile, BK=64, global_load_lds
//     width 16, mfma_i32_16x16x64_i8), epilogue adds rintf(b/bias_scale) and
//     rescales by bias_scale = act_scale * w_scale.

typedef int v4i __attribute__((ext_vector_type(4)));

__device__ __forceinline__ void async_copy16(const void* g, void* s) {
  __builtin_amdgcn_global_load_lds(
      (const __attribute__((address_space(1))) void*)g,
      (__attribute__((address_space(3))) void*)s, 16, 0, 0);
}

__global__ __launch_bounds__(256) void absmax_kernel(
    const float4* __restrict__ x, int n4, unsigned int* __restrict__ out) {
  float m = 0.0f;
  for (int i = blockIdx.x * blockDim.x + threadIdx.x; i < n4;
       i += gridDim.x * blockDim.x) {
    float4 v = x[i];
    m = fmaxf(m, fmaxf(fmaxf(fabsf(v.x), fabsf(v.y)),
                       fmaxf(fabsf(v.z), fabsf(v.w))));
  }
#pragma unroll
  for (int off = 32; off > 0; off >>= 1)
    m = fmaxf(m, __shfl_down(m, off, 64));
  if ((threadIdx.x & 63) == 0) atomicMax(out, __float_as_uint(m));
}

__global__ __launch_bounds__(256) void quant_kernel(
    const float4* __restrict__ x, int* __restrict__ q, int n4,
    const unsigned int* __restrict__ sbits) {
  int i = blockIdx.x * blockDim.x + threadIdx.x;
  if (i >= n4) return;
  // Matches reference exactly: scale = max(sat, 1e-8)/127 ; round(x/scale) ; clip
  const float scale = fmaxf(__uint_as_float(*sbits), 1e-8f) / 127.0f;
  float4 v = x[i];
  int a = (int)fminf(fmaxf(rintf(v.x / scale), -128.0f), 127.0f);
  int b = (int)fminf(fmaxf(rintf(v.y / scale), -128.0f), 127.0f);
  int c = (int)fminf(fmaxf(rintf(v.z / scale), -128.0f), 127.0f);
  int d = (int)fminf(fmaxf(rintf(v.w / scale), -128.0f), 127.0f);
  q[i] = (a & 255) | ((b & 255) << 8) | ((c & 255) << 16) | ((d & 255) << 24);
}

// C[m,n] = sum_k A[m,k]*B[n,k]  (A = x_int8 [M,K], B = w_int8 [N,K], both
// K-contiguous -> identical staging pattern for both operands).
__global__ __launch_bounds__(256) void i8_gemm_kernel(
    const signed char* __restrict__ Aq, const signed char* __restrict__ Bq,
    const float* __restrict__ bias, const unsigned int* __restrict__ sbits,
    float* __restrict__ out, int M, int N, int K) {
  __shared__ signed char Als[128 * 64];
  __shared__ signed char Bls[128 * 64];

  const int tid = threadIdx.x;
  const int lane = tid & 63;
  const int wave = tid >> 6;
  const int wm = (wave & 1) * 64;   // wave's 64x64 sub-tile
  const int wn = (wave >> 1) * 64;
  const int M0 = blockIdx.y * 128;
  const int N0 = blockIdx.x * 128;

  // Staging: 256 threads x 16B = 4 KiB/pass = 64 rows of 64B; 2 passes per tile.
  // LDS layout row-major [128][64] (no padding: global_load_lds requires
  // wave-uniform base + lane*16 contiguity).
  const int srow = tid >> 2;        // 0..63
  const int skb = (tid & 3) * 16;   // byte offset in 64B K-row

  const signed char* Ag = Aq + (size_t)(M0 + srow) * K + skb;
  const signed char* Bg = Bq + (size_t)(N0 + srow) * K + skb;
  signed char* AlsP = &Als[srow * 64 + skb];
  signed char* BlsP = &Bls[srow * 64 + skb];

  v4i acc[4][4] = {};

  const int r15 = lane & 15;
  const int kb = (lane >> 4) * 16;  // A/B operand: k = (lane>>4)*16 + j

  for (int kt = 0; kt < K; kt += 64) {
    __syncthreads();  // previous iter's ds_reads done before overwrite
    async_copy16(Ag + kt, AlsP);
    async_copy16(Ag + kt + (size_t)64 * K, AlsP + 64 * 64);
    async_copy16(Bg + kt, BlsP);
    async_copy16(Bg + kt + (size_t)64 * K, BlsP + 64 * 64);
    __syncthreads();  // compiler emits vmcnt(0) drain before s_barrier

    v4i af[4], bf[4];
#pragma unroll
    for (int t = 0; t < 4; ++t) {
      af[t] = *(const v4i*)&Als[(wm + t * 16 + r15) * 64 + kb];
      bf[t] = *(const v4i*)&Bls[(wn + t * 16 + r15) * 64 + kb];
    }
#pragma unroll
    for (int tm = 0; tm < 4; ++tm)
#pragma unroll
      for (int tn = 0; tn < 4; ++tn)
        acc[tm][tn] = __builtin_amdgcn_mfma_i32_16x16x64_i8(
            af[tm], bf[tn], acc[tm][tn], 0, 0, 0);
  }

  const float act_s = fmaxf(__uint_as_float(sbits[0]), 1e-8f) / 127.0f;
  const float w_s = fmaxf(__uint_as_float(sbits[1]), 1e-8f) / 127.0f;
  const float bscale = act_s * w_s;

  // C/D layout: col = lane&15, row = (lane>>4)*4 + reg  (shape-determined)
#pragma unroll
  for (int tn = 0; tn < 4; ++tn) {
    const int col = N0 + wn + tn * 16 + r15;
    const float fb = rintf(bias[col] / bscale);  // b_int (|.|~3e3, no clip needed)
#pragma unroll
    for (int tm = 0; tm < 4; ++tm) {
      const int row0 = M0 + wm + tm * 16 + (lane >> 4) * 4;
#pragma unroll
      for (int r = 0; r < 4; ++r) {
        out[(size_t)(row0 + r) * N + col] =
            ((float)acc[tm][tn][r] + fb) * bscale;
      }
    }
  }
}

extern "C" void kernel_launch(void* const* d_in, const int* in_sizes, int n_in,
                              void* d_out, int out_size, void* d_ws,
                              size_t ws_size, hipStream_t stream) {
  const float* x = (const float*)d_in[0];
  const float* W = (const float*)d_in[1];
  const float* b = (const float*)d_in[2];
  float* out = (float*)d_out;

  const int Dout = in_sizes[2];      // 4096
  const int K = in_sizes[1] / Dout;  // 4096
  const int M = in_sizes[0] / K;     // 8192
  const int N = Dout;

  // Workspace layout: [0..7] two absmax slots (float bits), 256-aligned int8
  // buffers after: xq = M*K bytes, wq = N*K bytes (~50.3 MB total).
  unsigned int* sbits = (unsigned int*)d_ws;
  signed char* xq = (signed char*)d_ws + 256;
  signed char* wq = xq + (size_t)M * K;

  hipMemsetAsync(d_ws, 0, 8, stream);  // ws is poisoned 0xAA -> must zero slots

  const int xn4 = in_sizes[0] / 4;
  const int wn4 = in_sizes[1] / 4;
  absmax_kernel<<<2048, 256, 0, stream>>>((const float4*)x, xn4, sbits + 0);
  absmax_kernel<<<2048, 256, 0, stream>>>((const float4*)W, wn4, sbits + 1);
  quant_kernel<<<(xn4 + 255) / 256, 256, 0, stream>>>((const float4*)x,
                                                      (int*)xq, xn4, sbits + 0);
  quant_kernel<<<(wn4 + 255) / 256, 256, 0, stream>>>((const float4*)W,
                                                      (int*)wq, wn4, sbits + 1);

  dim3 grid(N / 128, M / 128);
  i8_gemm_kernel<<<grid, 256, 0, stream>>>(xq, wq, b, sbits, out, M, N, K);
}

// Round 2
// 478.381 us; speedup vs baseline: 1.3766x; 1.3766x over previous
//
#include <hip/hip_runtime.h>
#include <cstdint>
#include <cstddef>

// Strategy (R2):
//  1) absmax(x) & absmax(W) in ONE dispatch: grid-stride per-block partials
//     written to distinct d_ws slots (NO atomics -> no cross-XCD contention),
//     then a 2-block final-reduce kernel produces sat_x, sat_w.
//  2) fused quantize: x -> int8 [M,K], W -> int8 [N,K] (exact reference ops:
//     scale = max(sat,1e-8)/127 ; rintf(v/scale) ; clip to [-128,127]).
//  3) int8 MFMA GEMM, m97 structure (128x128 tile, BK=64, global_load_lds
//     width 16, mfma_i32_16x16x64_i8) + XOR chunk swizzle to kill LDS bank
//     conflicts: LDS slot is forced to base+lane*16 by global_load_lds, so we
//     swizzle WHICH global 16B chunk each lane fetches, and de-swizzle the
//     ds_read address. slot = chunk ^ ((row>>1)&3).

typedef int v4i __attribute__((ext_vector_type(4)));

__device__ __forceinline__ void async_copy16(const void* g, void* s) {
  __builtin_amdgcn_global_load_lds(
      (const __attribute__((address_space(1))) void*)g,
      (__attribute__((address_space(3))) void*)s, 16, 0, 0);
}

__device__ __forceinline__ float block_max(float m) {
  __shared__ float smax[4];
#pragma unroll
  for (int off = 32; off > 0; off >>= 1)
    m = fmaxf(m, __shfl_down(m, off, 64));
  if ((threadIdx.x & 63) == 0) smax[threadIdx.x >> 6] = m;
  __syncthreads();
  return fmaxf(fmaxf(smax[0], smax[1]), fmaxf(smax[2], smax[3]));
}

#define NBX 1024  // partial blocks for x
#define NBW 512   // partial blocks for W

__global__ __launch_bounds__(256) void absmax_partial_kernel(
    const float4* __restrict__ x, int xn4, const float4* __restrict__ w,
    int wn4, float* __restrict__ px, float* __restrict__ pw) {
  const float4* src;
  float* dst;
  int n4, bid, nb;
  if (blockIdx.x < NBX) {
    src = x; n4 = xn4; dst = px; bid = blockIdx.x; nb = NBX;
  } else {
    src = w; n4 = wn4; dst = pw; bid = blockIdx.x - NBX; nb = NBW;
  }
  float m = 0.0f;
  for (int i = bid * 256 + threadIdx.x; i < n4; i += nb * 256) {
    float4 v = src[i];
    m = fmaxf(m, fmaxf(fmaxf(fabsf(v.x), fabsf(v.y)),
                       fmaxf(fabsf(v.z), fabsf(v.w))));
  }
  m = block_max(m);
  if (threadIdx.x == 0) dst[bid] = m;
}

__global__ __launch_bounds__(256) void absmax_final_kernel(
    const float* __restrict__ px, const float* __restrict__ pw,
    float* __restrict__ sat) {
  const float* src = (blockIdx.x == 0) ? px : pw;
  const int n = (blockIdx.x == 0) ? NBX : NBW;
  float m = 0.0f;
  for (int i = threadIdx.x; i < n; i += 256) m = fmaxf(m, src[i]);
  m = block_max(m);
  if (threadIdx.x == 0) sat[blockIdx.x] = m;
}

__global__ __launch_bounds__(256) void quant_fused_kernel(
    const float4* __restrict__ x, int xn4, const float4* __restrict__ w,
    int wn4, const float* __restrict__ sat, int* __restrict__ xq,
    int* __restrict__ wq) {
  int i = blockIdx.x * 256 + threadIdx.x;
  float4 v;
  float scale;
  int* q;
  int qi;
  if (i < xn4) {
    v = x[i];
    scale = fmaxf(sat[0], 1e-8f) / 127.0f;
    q = xq; qi = i;
  } else {
    int j = i - xn4;
    if (j >= wn4) return;
    v = w[j];
    scale = fmaxf(sat[1], 1e-8f) / 127.0f;
    q = wq; qi = j;
  }
  int a = (int)fminf(fmaxf(rintf(v.x / scale), -128.0f), 127.0f);
  int b = (int)fminf(fmaxf(rintf(v.y / scale), -128.0f), 127.0f);
  int c = (int)fminf(fmaxf(rintf(v.z / scale), -128.0f), 127.0f);
  int d = (int)fminf(fmaxf(rintf(v.w / scale), -128.0f), 127.0f);
  q[qi] = (a & 255) | ((b & 255) << 8) | ((c & 255) << 16) | ((d & 255) << 24);
}

// C[m,n] = sum_k A[m,k]*B[n,k]  (A = x_int8 [M,K], B = w_int8 [N,K]).
__global__ __launch_bounds__(256) void i8_gemm_kernel(
    const signed char* __restrict__ Aq, const signed char* __restrict__ Bq,
    const float* __restrict__ bias, const float* __restrict__ sat,
    float* __restrict__ out, int M, int N, int K) {
  __shared__ signed char Als[128 * 64];
  __shared__ signed char Bls[128 * 64];

  const int tid = threadIdx.x;
  const int lane = tid & 63;
  const int wave = tid >> 6;
  const int wm = (wave & 1) * 64;
  const int wn = (wave >> 1) * 64;
  const int M0 = blockIdx.y * 128;
  const int N0 = blockIdx.x * 128;

  // Staging: LDS slot is FORCED to wave_base + lane*16 by global_load_lds.
  // Slot (row, sb) holds global chunk cg = sb ^ ((row>>1)&3)  (XOR swizzle).
  const int srow = tid >> 2;                   // 0..63 (+64 second pass)
  const int sb = tid & 3;                      // LDS chunk slot
  const int cg = sb ^ ((srow >> 1) & 3);       // global chunk fetched here
                                               // (row+64 has same swizzle bits)
  const signed char* Ag = Aq + (size_t)(M0 + srow) * K + cg * 16;
  const signed char* Bg = Bq + (size_t)(N0 + srow) * K + cg * 16;
  signed char* AlsP = &Als[srow * 64 + sb * 16];
  signed char* BlsP = &Bls[srow * 64 + sb * 16];

  v4i acc[4][4] = {};

  // Read side: A-operand needs k-chunk c = lane>>4 of row (wm + t*16 + r15).
  // That data sits at slot c ^ ((row>>1)&3); since wm + t*16 is a multiple of
  // 16, (row>>1)&3 == (r15>>1)&3.
  const int r15 = lane & 15;
  const int swz = (r15 >> 1) & 3;
  const int kb = ((lane >> 4) ^ swz) * 16;     // de-swizzled LDS chunk offset

  for (int kt = 0; kt < K; kt += 64) {
    __syncthreads();
    async_copy16(Ag + kt, AlsP);
    async_copy16(Ag + kt + (size_t)64 * K, AlsP + 64 * 64);
    async_copy16(Bg + kt, BlsP);
    async_copy16(Bg + kt + (size_t)64 * K, BlsP + 64 * 64);
    __syncthreads();

    v4i af[4], bf[4];
#pragma unroll
    for (int t = 0; t < 4; ++t) {
      af[t] = *(const v4i*)&Als[(wm + t * 16 + r15) * 64 + kb];
      bf[t] = *(const v4i*)&Bls[(wn + t * 16 + r15) * 64 + kb];
    }
#pragma unroll
    for (int tm = 0; tm < 4; ++tm)
#pragma unroll
      for (int tn = 0; tn < 4; ++tn)
        acc[tm][tn] = __builtin_amdgcn_mfma_i32_16x16x64_i8(
            af[tm], bf[tn], acc[tm][tn], 0, 0, 0);
  }

  const float act_s = fmaxf(sat[0], 1e-8f) / 127.0f;
  const float w_s = fmaxf(sat[1], 1e-8f) / 127.0f;
  const float bscale = act_s * w_s;

  // C/D layout: col = lane&15, row = (lane>>4)*4 + reg
#pragma unroll
  for (int tn = 0; tn < 4; ++tn) {
    const int col = N0 + wn + tn * 16 + r15;
    const float fb = rintf(bias[col] / bscale);
#pragma unroll
    for (int tm = 0; tm < 4; ++tm) {
      const int row0 = M0 + wm + tm * 16 + (lane >> 4) * 4;
#pragma unroll
      for (int r = 0; r < 4; ++r) {
        out[(size_t)(row0 + r) * N + col] =
            ((float)acc[tm][tn][r] + fb) * bscale;
      }
    }
  }
}

extern "C" void kernel_launch(void* const* d_in, const int* in_sizes, int n_in,
                              void* d_out, int out_size, void* d_ws,
                              size_t ws_size, hipStream_t stream) {
  const float* x = (const float*)d_in[0];
  const float* W = (const float*)d_in[1];
  const float* b = (const float*)d_in[2];
  float* out = (float*)d_out;

  const int Dout = in_sizes[2];      // 4096
  const int K = in_sizes[1] / Dout;  // 4096
  const int M = in_sizes[0] / K;     // 8192
  const int N = Dout;

  // ws layout: sat[2] floats | px[NBX] | pw[NBW] | (8KB align) xq[M*K] | wq[N*K]
  float* sat = (float*)d_ws;
  float* px = sat + 16;
  float* pw = px + NBX;
  signed char* xq = (signed char*)d_ws + 8192;
  signed char* wq = xq + (size_t)M * K;

  const int xn4 = in_sizes[0] / 4;
  const int wn4 = in_sizes[1] / 4;

  absmax_partial_kernel<<<NBX + NBW, 256, 0, stream>>>(
      (const float4*)x, xn4, (const float4*)W, wn4, px, pw);
  absmax_final_kernel<<<2, 256, 0, stream>>>(px, pw, sat);
  quant_fused_kernel<<<(xn4 + wn4 + 255) / 256, 256, 0, stream>>>(
      (const float4*)x, xn4, (const float4*)W, wn4, sat, (int*)xq, (int*)wq);

  dim3 grid(N / 128, M / 128);
  i8_gemm_kernel<<<grid, 256, 0, stream>>>(xq, wq, b, sat, out, M, N, K);
}